// Round 1
// baseline (413.844 us; speedup 1.0000x reference)
//
#include <hip/hip_runtime.h>
#include <hip/hip_bf16.h>
#include <stdint.h>

#define BATCH   16384
#define IN_DIM  4096
#define OUT_DIM 64
#define KI      64              // input dims per LDS chunk
#define KCH     (3*KI)          // 192 k_eff per chunk
#define LDSTR   (KCH+8)         // 200 bf16 row stride (pad -> conflict-free-ish)
#define NCHUNK  (IN_DIM/KI)     // 64
#define SPLITK  4
#define CPB     (NCHUNK/SPLITK) // 16 chunks per block
#define MTILES  (BATCH/64)      // 256

typedef __attribute__((ext_vector_type(8))) short   short8;
typedef __attribute__((ext_vector_type(4))) float   floatx4;
typedef __attribute__((ext_vector_type(4))) uint32_t uintx4;

static __device__ __forceinline__ unsigned short f2bf(float f) {
    union { float f; uint32_t u; } v; v.f = f;
    uint32_t r = v.u + 0x7FFFu + ((v.u >> 16) & 1u);   // RNE
    return (unsigned short)(r >> 16);
}

// Closed-form degree-3 Cox-de Boor basis for knots [-1,-.5,0,.5,1,1] (derived
// exactly from the reference recursion, incl. where(den>0) drops):
//  B0: |x|<0.5 : 4|x|^3 - 4x^2 + 2/3 ; 0.5<=|x|<1 : (4/3)(1-|x|)^3 ; else 0
//  B1: x in [-0.5,0): (4/3)x^3+2x^2+x+1/6 ; [0,0.5): -(14/3)x^3+2x^2+x+1/6
//      [0.5,1): (22x^3-48x^2+30x-4)/3 ; else 0
static __device__ __forceinline__ void kan_features(float xv, float& b0, float& b1, float& sl) {
    float ax = fabsf(xv);
    float om = 1.0f - ax;
    float inner = (4.0f*ax - 4.0f)*(ax*ax) + (2.0f/3.0f);
    float outer = (4.0f/3.0f)*om*om*om;
    b0 = (ax < 0.5f) ? inner : outer;
    b0 = (ax < 1.0f) ? b0 : 0.0f;
    float c3  = (xv < 0.0f) ? (4.0f/3.0f) : (-14.0f/3.0f);
    float mid = ((c3*xv + 2.0f)*xv + 1.0f)*xv + (1.0f/6.0f);
    float hi  = (((22.0f*xv - 48.0f)*xv + 30.0f)*xv - 4.0f) * (1.0f/3.0f);
    b1 = (xv < 0.5f) ? mid : hi;
    b1 = (xv >= -0.5f && xv < 1.0f) ? b1 : 0.0f;
    float e = __expf(-xv);
    sl = xv * __builtin_amdgcn_rcpf(1.0f + e);
}

// Pre-pack weights to bf16, chunk-major: Wt[((ci*64 + j)*3 + t)*KI + il]
//   t=0: c[i][j][0]*ws[i][j], t=1: c[i][j][1]*ws[i][j], t=2: wb[i][j]
__global__ __launch_bounds__(256) void kan_prep(
        const float* __restrict__ c, const float* __restrict__ ws,
        const float* __restrict__ wb, unsigned short* __restrict__ Wt) {
    int idx = blockIdx.x * 256 + threadIdx.x;     // 0..98303 = 192 rows * 512 i-groups
    int row = idx >> 9;                           // j*3+t, 0..191
    int i   = (idx & 511) << 3;                   // 8 consecutive input dims
    int j   = row / 3;
    int t   = row - j*3;
    int ci  = i >> 6, il = i & 63;
    unsigned short pk[8];
    #pragma unroll
    for (int e = 0; e < 8; e++) {
        int ii = i + e;
        float v;
        if (t < 2) v = c[(size_t)ii*(OUT_DIM*2) + j*2 + t] * ws[(size_t)ii*OUT_DIM + j];
        else       v = wb[(size_t)ii*OUT_DIM + j];
        pk[e] = f2bf(v);
    }
    uintx4 d;
    d[0] = pk[0] | ((uint32_t)pk[1] << 16);
    d[1] = pk[2] | ((uint32_t)pk[3] << 16);
    d[2] = pk[4] | ((uint32_t)pk[5] << 16);
    d[3] = pk[6] | ((uint32_t)pk[7] << 16);
    *(uintx4*)(Wt + (size_t)((ci*64 + j)*3 + t)*KI + il) = d;
}

template<bool PRE>
__global__ __launch_bounds__(256) void kan_main(
    const float* __restrict__ x, const float* __restrict__ c,
    const float* __restrict__ ws, const float* __restrict__ wb,
    const unsigned short* __restrict__ Wt, float* __restrict__ out)
{
    __shared__ unsigned short Bs[OUT_DIM * LDSTR];   // 25.6 KB

    const int tid  = threadIdx.x;
    const int wave = tid >> 6;
    const int lane = tid & 63;
    const int m    = lane & 15;
    const int q    = lane >> 4;
    const int mt   = blockIdx.x & (MTILES - 1);
    const int kh   = blockIdx.x >> 8;                // SPLITK group
    const int row0 = mt * 64;
    const int r    = row0 + wave*16 + m;             // this lane's A-row
    const float* xrow = x + (size_t)r * IN_DIM;

    floatx4 acc[4] = {};

    for (int cc = 0; cc < CPB; cc++) {
        const int ci = kh * CPB + cc;
        const int i0 = ci * KI;

        __syncthreads();   // previous chunk's consumers done before overwrite

        if (PRE) {
            // contiguous 24 KB chunk copy, 1536 x 16B segs, 6 per thread
            const unsigned short* gW = Wt + (size_t)ci * (OUT_DIM * KCH);
            #pragma unroll
            for (int p = 0; p < 6; p++) {
                int seg = tid + p*256;
                uintx4 d = *(const uintx4*)(gW + seg*8);
                int j = seg / 24;
                *(uintx4*)&Bs[seg*8 + j*8] = d;      // = j*200 + u*8
            }
        } else {
            #pragma unroll
            for (int p = 0; p < 16; p++) {
                int idx = tid + p*256;               // 64 i x 64 j
                int j = idx & 63, i = idx >> 6;
                int gi = i0 + i;
                const float* cp = c + ((size_t)gi*OUT_DIM + j)*2;
                float c0 = cp[0], c1 = cp[1];
                float s  = ws[(size_t)gi*OUT_DIM + j];
                float b  = wb[(size_t)gi*OUT_DIM + j];
                Bs[j*LDSTR + i]        = f2bf(c0*s);
                Bs[j*LDSTR + KI + i]   = f2bf(c1*s);
                Bs[j*LDSTR + 2*KI + i] = f2bf(b);
            }
        }

        // ---- A fragments straight in registers (no LDS dependency, overlaps barrier) ----
        floatx4 xv[4];
        xv[0] = *(const floatx4*)(xrow + i0 + q*8);
        xv[1] = *(const floatx4*)(xrow + i0 + q*8 + 4);
        xv[2] = *(const floatx4*)(xrow + i0 + 32 + q*8);
        xv[3] = *(const floatx4*)(xrow + i0 + 32 + q*8 + 4);

        short8 af[6];   // ksteps: 0,1=B0(i 0..31,32..63) 2,3=B1 4,5=silu
        #pragma unroll
        for (int g = 0; g < 2; g++) {
            #pragma unroll
            for (int e = 0; e < 8; e++) {
                float v = xv[g*2 + (e >> 2)][e & 3];
                float b0, b1, sl;
                kan_features(v, b0, b1, sl);
                af[0 + g][e] = (short)f2bf(b0);
                af[2 + g][e] = (short)f2bf(b1);
                af[4 + g][e] = (short)f2bf(sl);
            }
        }

        __syncthreads();   // staging visible

        #pragma unroll
        for (int s = 0; s < 6; s++) {
            #pragma unroll
            for (int n = 0; n < 4; n++) {
                // B-frag: lane holds B[k=q*8+jj][n_col = n*16 + m], contiguous 16B
                short8 bf = *(const short8*)&Bs[(n*16 + m)*LDSTR + s*32 + q*8];
                acc[n] = __builtin_amdgcn_mfma_f32_16x16x32_bf16(af[s], bf, acc[n], 0, 0, 0);
            }
        }
    }

    // epilogue: C/D layout col=lane&15, row=quad*4+reg; SPLITK partials via atomics
    #pragma unroll
    for (int n = 0; n < 4; n++) {
        #pragma unroll
        for (int reg = 0; reg < 4; reg++) {
            int orow = row0 + wave*16 + q*4 + reg;
            atomicAdd(&out[(size_t)orow*OUT_DIM + n*16 + m], acc[n][reg]);
        }
    }
}

extern "C" void kernel_launch(void* const* d_in, const int* in_sizes, int n_in,
                              void* d_out, int out_size, void* d_ws, size_t ws_size,
                              hipStream_t stream) {
    const float* x  = (const float*)d_in[0];
    const float* c  = (const float*)d_in[1];
    const float* ws = (const float*)d_in[2];
    const float* wb = (const float*)d_in[3];
    float* out = (float*)d_out;

    hipMemsetAsync(d_out, 0, (size_t)out_size * sizeof(float), stream);

    const size_t need = (size_t)OUT_DIM * 3 * IN_DIM * 2;   // 1.5 MB packed weights
    if (ws_size >= need) {
        kan_prep<<<384, 256, 0, stream>>>(c, ws, wb, (unsigned short*)d_ws);
        kan_main<true><<<MTILES * SPLITK, 256, 0, stream>>>(
            x, c, ws, wb, (const unsigned short*)d_ws, out);
    } else {
        kan_main<false><<<MTILES * SPLITK, 256, 0, stream>>>(
            x, c, ws, wb, (const unsigned short*)d_ws, out);
    }
}

// Round 2
// 403.518 us; speedup vs baseline: 1.0256x; 1.0256x over previous
//
#include <hip/hip_runtime.h>
#include <hip/hip_bf16.h>
#include <stdint.h>

#define BATCH   16384
#define IN_DIM  4096
#define OUT_DIM 64
#define KI      64              // input dims per LDS chunk
#define KCH     (3*KI)          // 192 k_eff per chunk
#define NCHUNK  (IN_DIM/KI)     // 64
#define SPLITK  4
#define CPB     (NCHUNK/SPLITK) // 16 chunks per block
#define MTILES  (BATCH/64)      // 256
#define CHW     (OUT_DIM*KCH)   // 12288 shorts per weight chunk (24 KB)

typedef __attribute__((ext_vector_type(8))) short   short8;
typedef __attribute__((ext_vector_type(4))) float   floatx4;
typedef __attribute__((ext_vector_type(4))) uint32_t uintx4;

static __device__ __forceinline__ unsigned short f2bf(float f) {
    union { float f; uint32_t u; } v; v.f = f;
    uint32_t r = v.u + 0x7FFFu + ((v.u >> 16) & 1u);   // RNE
    return (unsigned short)(r >> 16);
}

// Closed-form degree-3 Cox-de Boor basis for knots [-1,-.5,0,.5,1,1]:
//  B0: |x|<0.5 : 4|x|^3-4x^2+2/3 ; 0.5<=|x|<1 : (4/3)(1-|x|)^3 ; else 0
//  B1: [-0.5,0): (4/3)x^3+2x^2+x+1/6 ; [0,0.5): -(14/3)x^3+2x^2+x+1/6
//      [0.5,1): (22x^3-48x^2+30x-4)/3 ; else 0
static __device__ __forceinline__ void kan_features(float xv, float& b0, float& b1, float& sl) {
    float ax = fabsf(xv);
    float a2 = ax*ax;
    float om = 1.0f - ax;
    float inner = __builtin_fmaf(__builtin_fmaf(4.0f, ax, -4.0f), a2, (2.0f/3.0f));
    float outer = (om*om) * (om * (4.0f/3.0f));
    b0 = (ax < 0.5f) ? inner : outer;
    b0 = (ax < 1.0f) ? b0 : 0.0f;
    float c3  = (xv < 0.0f) ? (4.0f/3.0f) : (-14.0f/3.0f);
    float mid = __builtin_fmaf(__builtin_fmaf(__builtin_fmaf(c3, xv, 2.0f), xv, 1.0f), xv, (1.0f/6.0f));
    float hi  = __builtin_fmaf(__builtin_fmaf(__builtin_fmaf(22.0f, xv, -48.0f), xv, 30.0f), xv, -4.0f) * (1.0f/3.0f);
    b1 = (xv < 0.5f) ? mid : hi;
    b1 = (xv >= -0.5f && xv < 1.0f) ? b1 : 0.0f;
    float e = __expf(-xv);
    sl = xv * __builtin_amdgcn_rcpf(1.0f + e);
}

// Swizzled pack: chunk ci holds 64 j-rows x 24 granules (16B each).
// granule(j, t, ig) lives at linear index  j*24 + ((t*8 + ig) ^ (j&7)),
// content = 8 consecutive il (il = ig*8..ig*8+7), value per (j,t,i):
//   t=0: c[i][j][0]*ws[i][j], t=1: c[i][j][1]*ws[i][j], t=2: wb[i][j]
__global__ __launch_bounds__(256) void kan_prep(
        const float* __restrict__ c, const float* __restrict__ ws,
        const float* __restrict__ wb, unsigned short* __restrict__ Wt) {
    int idx = blockIdx.x * 256 + threadIdx.x;     // 0..98303 = 192 rows * 512 i-groups
    int row = idx >> 9;                           // j*3+t, 0..191
    int i   = (idx & 511) << 3;                   // 8 consecutive input dims
    int j   = row / 3;
    int t   = row - j*3;
    int ci  = i >> 6, il0 = i & 63;
    unsigned short pk[8];
    #pragma unroll
    for (int e = 0; e < 8; e++) {
        int ii = i + e;
        float v;
        if (t < 2) v = c[(size_t)ii*(OUT_DIM*2) + j*2 + t] * ws[(size_t)ii*OUT_DIM + j];
        else       v = wb[(size_t)ii*OUT_DIM + j];
        pk[e] = f2bf(v);
    }
    uintx4 d;
    d[0] = pk[0] | ((uint32_t)pk[1] << 16);
    d[1] = pk[2] | ((uint32_t)pk[3] << 16);
    d[2] = pk[4] | ((uint32_t)pk[5] << 16);
    d[3] = pk[6] | ((uint32_t)pk[7] << 16);
    int g = j*24 + (((t << 3) | (il0 >> 3)) ^ (j & 7));
    *(uintx4*)(Wt + (size_t)ci*CHW + g*8) = d;
}

template<bool PRE>
__global__ __launch_bounds__(256, 4) void kan_main(
    const float* __restrict__ x, const float* __restrict__ c,
    const float* __restrict__ ws, const float* __restrict__ wb,
    const unsigned short* __restrict__ Wt, float* __restrict__ out)
{
    __shared__ unsigned short Bs[CHW];   // 24 KB, swizzled granule layout

    const int tid  = threadIdx.x;
    const int wave = tid >> 6;
    const int lane = tid & 63;
    const int m    = lane & 15;
    const int q    = lane >> 4;
    const int mt   = blockIdx.x & (MTILES - 1);
    const int kh   = blockIdx.x >> 8;                // SPLITK group
    const int row0 = mt * 64;
    const int r    = row0 + wave*16 + m;             // this lane's A-row
    const float* xrow = x + (size_t)r * IN_DIM;

    floatx4 acc[4] = {};

    // preload x for first chunk
    const int i00 = kh * CPB * KI;
    floatx4 xv[4];
    xv[0] = *(const floatx4*)(xrow + i00 + q*8);
    xv[1] = *(const floatx4*)(xrow + i00 + q*8 + 4);
    xv[2] = *(const floatx4*)(xrow + i00 + 32 + q*8);
    xv[3] = *(const floatx4*)(xrow + i00 + 32 + q*8 + 4);

    for (int cc = 0; cc < CPB; cc++) {
        const int ci = kh * CPB + cc;
        const int i0 = ci * KI;

        // ---- issue chunk cc's weight loads (L2-resident) early ----
        uintx4 stg[6];
        if (PRE) {
            const unsigned short* gW = Wt + (size_t)ci * CHW;
            #pragma unroll
            for (int p = 0; p < 6; p++)
                stg[p] = *(const uintx4*)(gW + (tid + p*256)*8);
        }

        // ---- issue NEXT chunk's x loads (HBM) — consumed next iteration ----
        const int inx = (cc + 1 < CPB) ? (i0 + KI) : i0;  // last iter: dummy reload
        floatx4 xvn[4];
        xvn[0] = *(const floatx4*)(xrow + inx + q*8);
        xvn[1] = *(const floatx4*)(xrow + inx + q*8 + 4);
        xvn[2] = *(const floatx4*)(xrow + inx + 32 + q*8);
        xvn[3] = *(const floatx4*)(xrow + inx + 32 + q*8 + 4);

        // ---- features from xv (no LDS/global dependency -> overlaps loads) ----
        short8 af[6];   // ksteps: 0,1=B0(i 0..31,32..63) 2,3=B1 4,5=silu
        #pragma unroll
        for (int g = 0; g < 2; g++) {
            #pragma unroll
            for (int e = 0; e < 8; e++) {
                float v = xv[g*2 + (e >> 2)][e & 3];
                float b0, b1, sl;
                kan_features(v, b0, b1, sl);
                af[0 + g][e] = (short)f2bf(b0);
                af[2 + g][e] = (short)f2bf(b1);
                af[4 + g][e] = (short)f2bf(sl);
            }
        }

        __syncthreads();   // previous chunk's LDS consumers done

        if (PRE) {
            #pragma unroll
            for (int p = 0; p < 6; p++)
                *(uintx4*)&Bs[(tid + p*256)*8] = stg[p];
        } else {
            #pragma unroll
            for (int p = 0; p < 16; p++) {
                int idx = tid + p*256;               // 64 i x 64 j
                int j = idx & 63, i = idx >> 6;
                int gi = i0 + i;
                const float* cp = c + ((size_t)gi*OUT_DIM + j)*2;
                float c0 = cp[0], c1 = cp[1];
                float s  = ws[(size_t)gi*OUT_DIM + j];
                float b  = wb[(size_t)gi*OUT_DIM + j];
                int jx = j & 7;
                Bs[j*KCH + ((0*8 + (i>>3)) ^ jx)*8 + (i&7)] = f2bf(c0*s);
                Bs[j*KCH + ((1*8 + (i>>3)) ^ jx)*8 + (i&7)] = f2bf(c1*s);
                Bs[j*KCH + ((2*8 + (i>>3)) ^ jx)*8 + (i&7)] = f2bf(b);
            }
        }

        __syncthreads();   // staging visible

        #pragma unroll
        for (int s = 0; s < 6; s++) {
            const int kb = (s >> 1)*8 + (s & 1)*4 + q;   // granule row index
            #pragma unroll
            for (int n = 0; n < 4; n++) {
                const int j = n*16 + m;                   // output col
                short8 bf = *(const short8*)&Bs[j*KCH + ((kb ^ (j & 7)) << 3)];
                acc[n] = __builtin_amdgcn_mfma_f32_16x16x32_bf16(af[s], bf, acc[n], 0, 0, 0);
            }
        }

        xv[0] = xvn[0]; xv[1] = xvn[1]; xv[2] = xvn[2]; xv[3] = xvn[3];
    }

    // epilogue: C/D layout col=lane&15, row=quad*4+reg; SPLITK partials via atomics
    #pragma unroll
    for (int n = 0; n < 4; n++) {
        #pragma unroll
        for (int reg = 0; reg < 4; reg++) {
            int orow = row0 + wave*16 + q*4 + reg;
            atomicAdd(&out[(size_t)orow*OUT_DIM + n*16 + m], acc[n][reg]);
        }
    }
}

extern "C" void kernel_launch(void* const* d_in, const int* in_sizes, int n_in,
                              void* d_out, int out_size, void* d_ws, size_t ws_size,
                              hipStream_t stream) {
    const float* x  = (const float*)d_in[0];
    const float* c  = (const float*)d_in[1];
    const float* ws = (const float*)d_in[2];
    const float* wb = (const float*)d_in[3];
    float* out = (float*)d_out;

    hipMemsetAsync(d_out, 0, (size_t)out_size * sizeof(float), stream);

    const size_t need = (size_t)NCHUNK * CHW * sizeof(unsigned short);   // 1.5 MB
    if (ws_size >= need) {
        kan_prep<<<384, 256, 0, stream>>>(c, ws, wb, (unsigned short*)d_ws);
        kan_main<true><<<MTILES * SPLITK, 256, 0, stream>>>(
            x, c, ws, wb, (const unsigned short*)d_ws, out);
    } else {
        kan_main<false><<<MTILES * SPLITK, 256, 0, stream>>>(
            x, c, ws, wb, (const unsigned short*)d_ws, out);
    }
}